// Round 1
// baseline (1630.450 us; speedup 1.0000x reference)
//
#include <hip/hip_runtime.h>

#define NVOX 20000
#define MPTS 64
#define CIN  10
#define NM   (NVOX*MPTS)      // 1,280,000
#define EPSBN 1e-3f

// ws layout (float offsets)
#define WS_SUMX   0     // 10
#define WS_SXX    16    // 55 packed lower-tri
#define WS_SCALE0 128   // 64
#define WS_SHIFT0 192   // 64
#define WS_SUM1   256   // 128
#define WS_SUMQ1  384   // 128
#define WS_SCALE1 512   // 128
#define WS_SHIFT1 640   // 128
#define WS_W1T    1024  // 16384

#define ZSTR 68
#define XSTR 12
#define RSTR 132

__global__ void k_transpose(const float* __restrict__ w1, float* __restrict__ w1t) {
    int idx = blockIdx.x * 256 + threadIdx.x;
    if (idx < 128 * 128) {
        int o = idx >> 7, c = idx & 127;
        w1t[c * 128 + o] = w1[idx];
    }
}

__global__ void k_stats0(const float* __restrict__ x, float* __restrict__ ws) {
    float sx[CIN];
    float sxx[55];
#pragma unroll
    for (int i = 0; i < CIN; i++) sx[i] = 0.f;
#pragma unroll
    for (int k = 0; k < 55; k++) sxx[k] = 0.f;

    int tid = blockIdx.x * blockDim.x + threadIdx.x;
    int stride = gridDim.x * blockDim.x;
    for (int p = tid; p < NM; p += stride) {
        const float* xp = x + p * CIN;
        float v[CIN];
#pragma unroll
        for (int i = 0; i < CIN; i++) v[i] = xp[i];
#pragma unroll
        for (int i = 0; i < CIN; i++) sx[i] += v[i];
#pragma unroll
        for (int i = 0; i < CIN; i++)
#pragma unroll
            for (int j = 0; j <= i; j++)
                sxx[i * (i + 1) / 2 + j] += v[i] * v[j];
    }

    int lane = threadIdx.x & 63;
#pragma unroll
    for (int i = 0; i < CIN; i++) {
        float v = sx[i];
#pragma unroll
        for (int off = 32; off; off >>= 1) v += __shfl_xor(v, off, 64);
        if (lane == 0) atomicAdd(&ws[WS_SUMX + i], v);
    }
#pragma unroll
    for (int k = 0; k < 55; k++) {
        float v = sxx[k];
#pragma unroll
        for (int off = 32; off; off >>= 1) v += __shfl_xor(v, off, 64);
        if (lane == 0) atomicAdd(&ws[WS_SXX + k], v);
    }
}

__global__ void k_finalize0(float* __restrict__ ws, const float* __restrict__ w0,
                            const float* __restrict__ gamma0, const float* __restrict__ beta0) {
    int o = threadIdx.x;  // 64 threads
    float w[CIN];
#pragma unroll
    for (int i = 0; i < CIN; i++) w[i] = w0[o * CIN + i];
    float m = 0.f;
#pragma unroll
    for (int i = 0; i < CIN; i++) m += w[i] * ws[WS_SUMX + i];
    m *= (1.f / NM);
    float q = 0.f;
#pragma unroll
    for (int i = 0; i < CIN; i++)
#pragma unroll
        for (int j = 0; j <= i; j++)
            q += ((i == j) ? 1.f : 2.f) * w[i] * w[j] * ws[WS_SXX + i * (i + 1) / 2 + j];
    q *= (1.f / NM);
    float var = q - m * m;
    float scale = gamma0[o] * rsqrtf(var + EPSBN);
    ws[WS_SCALE0 + o] = scale;
    ws[WS_SHIFT0 + o] = beta0[o] - m * scale;
}

__global__ void k_finalize1(float* __restrict__ ws, const float* __restrict__ gamma1,
                            const float* __restrict__ beta1) {
    int o = threadIdx.x;  // 128 threads
    float m = ws[WS_SUM1 + o] * (1.f / NM);
    float q = ws[WS_SUMQ1 + o] * (1.f / NM);
    float var = q - m * m;
    float scale = gamma1[o] * rsqrtf(var + EPSBN);
    ws[WS_SCALE1 + o] = scale;
    ws[WS_SHIFT1 + o] = beta1[o] - m * scale;
}

// One block = 256 threads, grid-strides over voxels.
// Per voxel: stage x (64x10) -> LDS; layer0 -> zT[c][p] (c=0..63 pointwise, transposed);
// agg[64] = max over p; d[o] = sum_c W1[o][64+c]*agg[c]; then 64x128 GEMM over c<64
// with per-thread 4p x 8o register tile. STATS: accumulate sum/sumsq of y1 per channel.
// FINAL: BN1+ReLU, max over p, write out[n][128].
template <bool STATS>
__global__ __launch_bounds__(256) void k_pass(const float* __restrict__ x,
                                              const float* __restrict__ w0,
                                              float* __restrict__ ws,
                                              float* __restrict__ out) {
    __shared__ float xs[MPTS * XSTR];     // 3072 B
    __shared__ float zT[MPTS * ZSTR];     // 17408 B  (zT[c][p], c<64)
    __shared__ float agg[64];             // 256 B
    __shared__ float dsh[2 * 128];        // 1024 B
    __shared__ float red[16 * RSTR];      // 8448 B

    const int t = threadIdx.x;
    const int o64 = t & 63;
    const int pblk = t >> 6;  // 0..3
    const int pg = t >> 4;    // 0..15
    const int og = t & 15;    // 0..15
    const float* __restrict__ w1t = ws + WS_W1T;

    // persistent per-thread constants
    float w0r[CIN];
#pragma unroll
    for (int i = 0; i < CIN; i++) w0r[i] = w0[o64 * CIN + i];
    const float sc0 = ws[WS_SCALE0 + o64];
    const float sh0 = ws[WS_SHIFT0 + o64];

    float sc1[8], sh1[8];
    if (!STATS) {
#pragma unroll
        for (int j = 0; j < 8; j++) {
            sc1[j] = ws[WS_SCALE1 + og * 8 + j];
            sh1[j] = ws[WS_SHIFT1 + og * 8 + j];
        }
    }
    float as_[8], aq[8];
    if (STATS) {
#pragma unroll
        for (int j = 0; j < 8; j++) { as_[j] = 0.f; aq[j] = 0.f; }
    }

    for (int n = blockIdx.x; n < NVOX; n += gridDim.x) {
        // ---- stage x tile ----
        const float* __restrict__ xv = x + (size_t)n * (MPTS * CIN);
        for (int idx = t; idx < MPTS * CIN; idx += 256) {
            int p = idx / CIN;
            int c = idx - p * CIN;
            xs[p * XSTR + c] = xv[idx];
        }
        __syncthreads();

        // ---- layer 0: each thread does channel o64 for 16 points ----
        float pm = 0.f;
#pragma unroll
        for (int k = 0; k < 16; k++) {
            int p = pblk * 16 + k;
            float4 a = *(const float4*)&xs[p * XSTR];
            float4 b = *(const float4*)&xs[p * XSTR + 4];
            float2 c2 = *(const float2*)&xs[p * XSTR + 8];
            float y = a.x * w0r[0] + a.y * w0r[1] + a.z * w0r[2] + a.w * w0r[3] +
                      b.x * w0r[4] + b.y * w0r[5] + b.z * w0r[6] + b.w * w0r[7] +
                      c2.x * w0r[8] + c2.y * w0r[9];
            float v = fmaxf(y * sc0 + sh0, 0.f);
            zT[o64 * ZSTR + p] = v;
            pm = fmaxf(pm, v);
        }
        red[pblk * 64 + o64] = pm;
        __syncthreads();
        if (t < 64) {
            agg[t] = fmaxf(fmaxf(red[t], red[64 + t]), fmaxf(red[128 + t], red[192 + t]));
        }
        __syncthreads();

        // ---- d[o] = sum_{c<64} W1[o][64+c] * agg[c], split over 2 halves ----
        {
            int o = t & 127;
            int h = t >> 7;
            float dp = 0.f;
#pragma unroll
            for (int c = 0; c < 32; c++) {
                int cc = h * 32 + c;
                dp += w1t[(64 + cc) * 128 + o] * agg[cc];
            }
            dsh[h * 128 + o] = dp;
        }
        __syncthreads();

        // ---- GEMM: y1[p][o] = d[o] + sum_{c<64} zT[c][p]*W1T[c][o] ----
        float acc[4][8];
#pragma unroll
        for (int j = 0; j < 8; j++) {
            float d = dsh[og * 8 + j] + dsh[128 + og * 8 + j];
#pragma unroll
            for (int i = 0; i < 4; i++) acc[i][j] = d;
        }
#pragma unroll 4
        for (int c = 0; c < 64; c++) {
            float4 zv = *(const float4*)&zT[c * ZSTR + pg * 4];
            float4 wa = *(const float4*)&w1t[c * 128 + og * 8];
            float4 wb = *(const float4*)&w1t[c * 128 + og * 8 + 4];
#pragma unroll
            for (int i = 0; i < 4; i++) {
                float z = (i == 0) ? zv.x : (i == 1) ? zv.y : (i == 2) ? zv.z : zv.w;
                acc[i][0] += z * wa.x; acc[i][1] += z * wa.y;
                acc[i][2] += z * wa.z; acc[i][3] += z * wa.w;
                acc[i][4] += z * wb.x; acc[i][5] += z * wb.y;
                acc[i][6] += z * wb.z; acc[i][7] += z * wb.w;
            }
        }

        if (STATS) {
#pragma unroll
            for (int i = 0; i < 4; i++)
#pragma unroll
                for (int j = 0; j < 8; j++) {
                    float y = acc[i][j];
                    as_[j] += y;
                    aq[j] += y * y;
                }
        } else {
#pragma unroll
            for (int j = 0; j < 8; j++) {
                float m0 = 0.f;
#pragma unroll
                for (int i = 0; i < 4; i++)
                    m0 = fmaxf(m0, fmaxf(acc[i][j] * sc1[j] + sh1[j], 0.f));
                red[pg * RSTR + og * 8 + j] = m0;
            }
            __syncthreads();
            if (t < 128) {
                float m = red[t];
#pragma unroll
                for (int g = 1; g < 16; g++) m = fmaxf(m, red[g * RSTR + t]);
                out[(size_t)n * 128 + t] = m;
            }
            // next-iteration post-staging barrier orders red reads vs rewrites
        }
    }

    if (STATS) {
        __syncthreads();
#pragma unroll
        for (int j = 0; j < 8; j++) red[pg * RSTR + og * 8 + j] = as_[j];
        __syncthreads();
        if (t < 16) {
#pragma unroll
            for (int j = 0; j < 8; j++) {
                float s = 0.f;
                for (int g = 0; g < 16; g++) s += red[g * RSTR + t * 8 + j];
                atomicAdd(&ws[WS_SUM1 + t * 8 + j], s);
            }
        }
        __syncthreads();
#pragma unroll
        for (int j = 0; j < 8; j++) red[pg * RSTR + og * 8 + j] = aq[j];
        __syncthreads();
        if (t < 16) {
#pragma unroll
            for (int j = 0; j < 8; j++) {
                float s = 0.f;
                for (int g = 0; g < 16; g++) s += red[g * RSTR + t * 8 + j];
                atomicAdd(&ws[WS_SUMQ1 + t * 8 + j], s);
            }
        }
    }
}

extern "C" void kernel_launch(void* const* d_in, const int* in_sizes, int n_in,
                              void* d_out, int out_size, void* d_ws, size_t ws_size,
                              hipStream_t stream) {
    (void)in_sizes; (void)n_in; (void)out_size; (void)ws_size;
    const float* x      = (const float*)d_in[0];
    const float* W0     = (const float*)d_in[1];
    const float* gamma0 = (const float*)d_in[2];
    const float* beta0  = (const float*)d_in[3];
    const float* W1     = (const float*)d_in[4];
    const float* gamma1 = (const float*)d_in[5];
    const float* beta1  = (const float*)d_in[6];
    float* out = (float*)d_out;
    float* ws  = (float*)d_ws;

    hipMemsetAsync(d_ws, 0, 4096, stream);                       // zero accumulators
    k_transpose<<<64, 256, 0, stream>>>(W1, ws + WS_W1T);
    k_stats0<<<256, 256, 0, stream>>>(x, ws);
    k_finalize0<<<1, 64, 0, stream>>>(ws, W0, gamma0, beta0);
    k_pass<true><<<1280, 256, 0, stream>>>(x, W0, ws, nullptr);  // layer-1 stats
    k_finalize1<<<1, 128, 0, stream>>>(ws, gamma1, beta1);
    k_pass<false><<<1280, 256, 0, stream>>>(x, W0, ws, out);     // final output
}

// Round 2
// 666.265 us; speedup vs baseline: 2.4472x; 2.4472x over previous
//
#include <hip/hip_runtime.h>

#define NVOX 20000
#define MPTS 64
#define CIN  10
#define NM   (NVOX*MPTS)      // 1,280,000
#define EPSBN 1e-3f

// ws layout (float offsets)
#define WS_SUMX   0     // 10
#define WS_SXX    16    // 55 packed lower-tri
#define WS_SCALE0 128   // 64
#define WS_SHIFT0 192   // 64
#define WS_SUM1   256   // 128
#define WS_SUMQ1  384   // 128
#define WS_SCALE1 512   // 128
#define WS_SHIFT1 640   // 128

typedef short bf16x8 __attribute__((ext_vector_type(8)));
typedef float f32x4  __attribute__((ext_vector_type(4)));

__device__ __forceinline__ unsigned short f2bf(float f) {
    union { float f; unsigned u; } v; v.f = f;
    unsigned r = v.u + 0x7FFFu + ((v.u >> 16) & 1u);   // RNE to bf16
    return (unsigned short)(r >> 16);
}

__global__ void k_stats0(const float* __restrict__ x, float* __restrict__ ws) {
    float sx[CIN];
    float sxx[55];
#pragma unroll
    for (int i = 0; i < CIN; i++) sx[i] = 0.f;
#pragma unroll
    for (int k = 0; k < 55; k++) sxx[k] = 0.f;

    int tid = blockIdx.x * blockDim.x + threadIdx.x;
    int stride = gridDim.x * blockDim.x;
    for (int p = tid; p < NM; p += stride) {
        const float* xp = x + p * CIN;
        float v[CIN];
#pragma unroll
        for (int i = 0; i < CIN; i++) v[i] = xp[i];
#pragma unroll
        for (int i = 0; i < CIN; i++) sx[i] += v[i];
#pragma unroll
        for (int i = 0; i < CIN; i++)
#pragma unroll
            for (int j = 0; j <= i; j++)
                sxx[i * (i + 1) / 2 + j] += v[i] * v[j];
    }

    int lane = threadIdx.x & 63;
#pragma unroll
    for (int i = 0; i < CIN; i++) {
        float v = sx[i];
#pragma unroll
        for (int off = 32; off; off >>= 1) v += __shfl_xor(v, off, 64);
        if (lane == 0) atomicAdd(&ws[WS_SUMX + i], v);
    }
#pragma unroll
    for (int k = 0; k < 55; k++) {
        float v = sxx[k];
#pragma unroll
        for (int off = 32; off; off >>= 1) v += __shfl_xor(v, off, 64);
        if (lane == 0) atomicAdd(&ws[WS_SXX + k], v);
    }
}

__global__ void k_finalize0(float* __restrict__ ws, const float* __restrict__ w0,
                            const float* __restrict__ gamma0, const float* __restrict__ beta0) {
    int o = threadIdx.x;  // 64 threads
    float w[CIN];
#pragma unroll
    for (int i = 0; i < CIN; i++) w[i] = w0[o * CIN + i];
    float m = 0.f;
#pragma unroll
    for (int i = 0; i < CIN; i++) m += w[i] * ws[WS_SUMX + i];
    m *= (1.f / NM);
    float q = 0.f;
#pragma unroll
    for (int i = 0; i < CIN; i++)
#pragma unroll
        for (int j = 0; j <= i; j++)
            q += ((i == j) ? 1.f : 2.f) * w[i] * w[j] * ws[WS_SXX + i * (i + 1) / 2 + j];
    q *= (1.f / NM);
    float var = q - m * m;
    float scale = gamma0[o] * rsqrtf(var + EPSBN);
    ws[WS_SCALE0 + o] = scale;
    ws[WS_SHIFT0 + o] = beta0[o] - m * scale;
}

__global__ void k_finalize1(float* __restrict__ ws, const float* __restrict__ gamma1,
                            const float* __restrict__ beta1) {
    int o = threadIdx.x;  // 128 threads
    float m = ws[WS_SUM1 + o] * (1.f / NM);
    float q = ws[WS_SUMQ1 + o] * (1.f / NM);
    float var = q - m * m;
    float scale = gamma1[o] * rsqrtf(var + EPSBN);
    ws[WS_SCALE1 + o] = scale;
    ws[WS_SHIFT1 + o] = beta1[o] - m * scale;
}

// 256 threads = 4 waves, grid-stride over voxels.
// Layer 0 on VALU (thread = channel x 16 points), z -> LDS bf16 [64][72] (144B stride,
// min-conflict for the A-fragment ds_read_b128 pattern). Layer-1 GEMM on MFMA:
// y1(64p x 128o, K=128) where K 0..63 = z and K 64..127 = broadcast agg (the concat).
// W1 fragments live in registers (loaded once per block). Wave w owns output cols
// 32w..32w+31 (njl=0,1). The rep contribution is computed once per njl (dacc) since
// its A rows are identical, then reused as the accumulator init for all 4 mi tiles.
template <bool STATS>
__global__ __launch_bounds__(256) void k_pass(const float* __restrict__ x,
                                              const float* __restrict__ w0,
                                              const float* __restrict__ w1,
                                              float* __restrict__ ws,
                                              float* __restrict__ out) {
    __shared__ float xs[MPTS * CIN];              // 2560 B
    __shared__ unsigned short zB[MPTS * 72];      // 9216 B
    __shared__ unsigned short aggB[64];           // 128 B
    __shared__ float red[4 * 64];                 // 1024 B

    const int t  = threadIdx.x;
    const int l  = t & 63;
    const int w  = t >> 6;   // wave 0..3
    const int lr = l & 15;
    const int lg = l >> 4;

    // ---- layer-0 role: channel ch for 16 points (quarter q) ----
    const int ch = t & 63;
    const int q  = t >> 6;
    float w0r[CIN];
#pragma unroll
    for (int i = 0; i < CIN; i++) w0r[i] = w0[ch * CIN + i];
    const float sc0 = ws[WS_SCALE0 + ch];
    const float sh0 = ws[WS_SHIFT0 + ch];

    // ---- W1 register fragments: wfrag[njl][ks]; col = 32w+16njl+lr, k = 32ks+8lg+j ----
    bf16x8 wfrag[2][4];
#pragma unroll
    for (int njl = 0; njl < 2; njl++) {
        const float* wrow = w1 + (32 * w + 16 * njl + lr) * 128;
#pragma unroll
        for (int ks = 0; ks < 4; ks++) {
            float4 a = *(const float4*)(wrow + 32 * ks + 8 * lg);
            float4 b = *(const float4*)(wrow + 32 * ks + 8 * lg + 4);
            bf16x8 f;
            f[0] = (short)f2bf(a.x); f[1] = (short)f2bf(a.y);
            f[2] = (short)f2bf(a.z); f[3] = (short)f2bf(a.w);
            f[4] = (short)f2bf(b.x); f[5] = (short)f2bf(b.y);
            f[6] = (short)f2bf(b.z); f[7] = (short)f2bf(b.w);
            wfrag[njl][ks] = f;
        }
    }

    float sc1[2], sh1[2];
    if (!STATS) {
#pragma unroll
        for (int njl = 0; njl < 2; njl++) {
            int col = 32 * w + 16 * njl + lr;
            sc1[njl] = ws[WS_SCALE1 + col];
            sh1[njl] = ws[WS_SHIFT1 + col];
        }
    }
    float as_[2] = {0.f, 0.f}, aq[2] = {0.f, 0.f};

    for (int n = blockIdx.x; n < NVOX; n += gridDim.x) {
        // ---- stage x (640 floats, vectorized) ----
        const float* xv = x + (size_t)n * (MPTS * CIN);
        if (t < 160) ((float4*)xs)[t] = ((const float4*)xv)[t];
        __syncthreads();

        // ---- layer 0 ----
        float pm = 0.f;
#pragma unroll
        for (int k = 0; k < 16; k++) {
            int p = q * 16 + k;
            const float* xp = xs + p * CIN;
            float y = xp[0] * w0r[0] + xp[1] * w0r[1] + xp[2] * w0r[2] + xp[3] * w0r[3] +
                      xp[4] * w0r[4] + xp[5] * w0r[5] + xp[6] * w0r[6] + xp[7] * w0r[7] +
                      xp[8] * w0r[8] + xp[9] * w0r[9];
            float v = fmaxf(fmaf(y, sc0, sh0), 0.f);
            zB[p * 72 + ch] = f2bf(v);
            pm = fmaxf(pm, v);
        }
        red[q * 64 + ch] = pm;
        __syncthreads();
        if (t < 64) {
            float m = fmaxf(fmaxf(red[t], red[64 + t]), fmaxf(red[128 + t], red[192 + t]));
            aggB[t] = f2bf(m);
        }
        __syncthreads();

        // ---- MFMA GEMM ----
        bf16x8 afrag[4][2];
#pragma unroll
        for (int mi = 0; mi < 4; mi++)
#pragma unroll
            for (int ks = 0; ks < 2; ks++)
                afrag[mi][ks] = *(const bf16x8*)&zB[(16 * mi + lr) * 72 + 32 * ks + 8 * lg];
        bf16x8 gfrag[2];
#pragma unroll
        for (int ksh = 0; ksh < 2; ksh++)
            gfrag[ksh] = *(const bf16x8*)&aggB[32 * ksh + 8 * lg];

        f32x4 dacc[2];
#pragma unroll
        for (int njl = 0; njl < 2; njl++) {
            f32x4 zz = {0.f, 0.f, 0.f, 0.f};
            zz = __builtin_amdgcn_mfma_f32_16x16x32_bf16(gfrag[0], wfrag[njl][2], zz, 0, 0, 0);
            dacc[njl] = __builtin_amdgcn_mfma_f32_16x16x32_bf16(gfrag[1], wfrag[njl][3], zz, 0, 0, 0);
        }

        float vm[2] = {0.f, 0.f};
#pragma unroll
        for (int njl = 0; njl < 2; njl++) {
#pragma unroll
            for (int mi = 0; mi < 4; mi++) {
                f32x4 acc = dacc[njl];
                acc = __builtin_amdgcn_mfma_f32_16x16x32_bf16(afrag[mi][0], wfrag[njl][0], acc, 0, 0, 0);
                acc = __builtin_amdgcn_mfma_f32_16x16x32_bf16(afrag[mi][1], wfrag[njl][1], acc, 0, 0, 0);
                if (STATS) {
#pragma unroll
                    for (int r = 0; r < 4; r++) { as_[njl] += acc[r]; aq[njl] += acc[r] * acc[r]; }
                } else {
#pragma unroll
                    for (int r = 0; r < 4; r++)
                        vm[njl] = fmaxf(vm[njl], fmaxf(fmaf(acc[r], sc1[njl], sh1[njl]), 0.f));
                }
            }
        }

        if (!STATS) {
#pragma unroll
            for (int njl = 0; njl < 2; njl++) {
                float v = vm[njl];
                v = fmaxf(v, __shfl_xor(v, 16));
                v = fmaxf(v, __shfl_xor(v, 32));
                if (l < 16) out[(size_t)n * 128 + 32 * w + 16 * njl + l] = v;
            }
        }
        // no loop-end barrier needed: next-iter zB/red/aggB writes are gated by
        // B1(n+1)/B2(n+1), which require all waves past this iteration's reads.
    }

    if (STATS) {
#pragma unroll
        for (int njl = 0; njl < 2; njl++) {
            float s = as_[njl];
            s += __shfl_xor(s, 16); s += __shfl_xor(s, 32);
            float qq = aq[njl];
            qq += __shfl_xor(qq, 16); qq += __shfl_xor(qq, 32);
            if (l < 16) {
                atomicAdd(&ws[WS_SUM1 + 32 * w + 16 * njl + l], s);
                atomicAdd(&ws[WS_SUMQ1 + 32 * w + 16 * njl + l], qq);
            }
        }
    }
}

extern "C" void kernel_launch(void* const* d_in, const int* in_sizes, int n_in,
                              void* d_out, int out_size, void* d_ws, size_t ws_size,
                              hipStream_t stream) {
    (void)in_sizes; (void)n_in; (void)out_size; (void)ws_size;
    const float* x      = (const float*)d_in[0];
    const float* W0     = (const float*)d_in[1];
    const float* gamma0 = (const float*)d_in[2];
    const float* beta0  = (const float*)d_in[3];
    const float* W1     = (const float*)d_in[4];
    const float* gamma1 = (const float*)d_in[5];
    const float* beta1  = (const float*)d_in[6];
    float* out = (float*)d_out;
    float* ws  = (float*)d_ws;

    hipMemsetAsync(d_ws, 0, 4096, stream);                        // zero accumulators
    k_stats0<<<256, 256, 0, stream>>>(x, ws);
    k_finalize0<<<1, 64, 0, stream>>>(ws, W0, gamma0, beta0);
    k_pass<true><<<1536, 256, 0, stream>>>(x, W0, W1, ws, nullptr);   // layer-1 stats
    k_finalize1<<<1, 128, 0, stream>>>(ws, gamma1, beta1);
    k_pass<false><<<1536, 256, 0, stream>>>(x, W0, W1, ws, out);      // final output
}

// Round 3
// 244.035 us; speedup vs baseline: 6.6812x; 2.7302x over previous
//
#include <hip/hip_runtime.h>

#define NVOX 20000
#define MPTS 64
#define CIN  10
#define NM   (NVOX*MPTS)      // 1,280,000
#define EPSBN 1e-3f

// ws param layout (float offsets) — only 512 floats used
#define WS_SCALE0 0     // 64
#define WS_SHIFT0 64    // 64
#define WS_SCALE1 128   // 128
#define WS_SHIFT1 256   // 128

// d_out (2.56M floats) doubles as stream-ordered scratch for reduction partials;
// k_pass<false> fully rewrites it at the end.
#define NB0   512       // stats0 blocks -> P0 partials [NB0][P0STR]
#define P0STR 72        // 65 used
#define NB1   1024      // pass<true> blocks -> P1 partials [NB1][256] (sum|sumq)
#define NBF   1536      // pass<false> blocks

typedef short bf16x8 __attribute__((ext_vector_type(8)));
typedef float f32x4  __attribute__((ext_vector_type(4)));

__device__ __forceinline__ unsigned short f2bf(float f) {
    union { float f; unsigned u; } v; v.f = f;
    unsigned r = v.u + 0x7FFFu + ((v.u >> 16) & 1u);   // RNE to bf16
    return (unsigned short)(r >> 16);
}

// x-moment pass: Sx (10) + Sxx (55 packed) via per-block partials, NO atomics.
__global__ __launch_bounds__(256) void k_stats0(const float* __restrict__ x,
                                                float* __restrict__ p0) {
    __shared__ float sm[4][P0STR];
    float sx[CIN];
    float sxx[55];
#pragma unroll
    for (int i = 0; i < CIN; i++) sx[i] = 0.f;
#pragma unroll
    for (int k = 0; k < 55; k++) sxx[k] = 0.f;

    const int t = threadIdx.x;
    const int tid = blockIdx.x * 256 + t;

    // 2 points per thread per iter: 5 aligned float4 loads (80 B)
    for (int g = tid; g < NM / 2; g += NB0 * 256) {
        const float4* xp = (const float4*)(x + (size_t)g * 20);
        float4 a = xp[0], b = xp[1], c = xp[2], d = xp[3], e = xp[4];
        float v0[CIN] = {a.x, a.y, a.z, a.w, b.x, b.y, b.z, b.w, c.x, c.y};
        float v1[CIN] = {c.z, c.w, d.x, d.y, d.z, d.w, e.x, e.y, e.z, e.w};
#pragma unroll
        for (int i = 0; i < CIN; i++) sx[i] += v0[i] + v1[i];
#pragma unroll
        for (int i = 0; i < CIN; i++)
#pragma unroll
            for (int j = 0; j <= i; j++)
                sxx[i * (i + 1) / 2 + j] += v0[i] * v0[j] + v1[i] * v1[j];
    }

    const int l = t & 63, w = t >> 6;
#pragma unroll
    for (int i = 0; i < CIN; i++) {
        float v = sx[i];
#pragma unroll
        for (int off = 32; off; off >>= 1) v += __shfl_xor(v, off, 64);
        if (l == 0) sm[w][i] = v;
    }
#pragma unroll
    for (int k = 0; k < 55; k++) {
        float v = sxx[k];
#pragma unroll
        for (int off = 32; off; off >>= 1) v += __shfl_xor(v, off, 64);
        if (l == 0) sm[w][10 + k] = v;
    }
    __syncthreads();
    if (t < 65)
        p0[blockIdx.x * P0STR + t] = sm[0][t] + sm[1][t] + sm[2][t] + sm[3][t];
}

// stage-2 reduce of P0 + BN0 fold (single block, 256 threads)
__global__ void k_finalize0(const float* __restrict__ p0, float* __restrict__ ws,
                            const float* __restrict__ w0,
                            const float* __restrict__ gamma0, const float* __restrict__ beta0) {
    __shared__ float s[P0STR];
    const int t = threadIdx.x;
    if (t < 65) {
        float acc = 0.f;
#pragma unroll 8
        for (int r = 0; r < NB0; r++) acc += p0[r * P0STR + t];  // coalesced across t
        s[t] = acc;
    }
    __syncthreads();
    if (t < 64) {
        float w[CIN];
#pragma unroll
        for (int i = 0; i < CIN; i++) w[i] = w0[t * CIN + i];
        float m = 0.f;
#pragma unroll
        for (int i = 0; i < CIN; i++) m += w[i] * s[i];
        m *= (1.f / NM);
        float q = 0.f;
#pragma unroll
        for (int i = 0; i < CIN; i++)
#pragma unroll
            for (int j = 0; j <= i; j++)
                q += ((i == j) ? 1.f : 2.f) * w[i] * w[j] * s[10 + i * (i + 1) / 2 + j];
        q *= (1.f / NM);
        float var = q - m * m;
        float scale = gamma0[t] * rsqrtf(var + EPSBN);
        ws[WS_SCALE0 + t] = scale;
        ws[WS_SHIFT0 + t] = beta0[t] - m * scale;
    }
}

// stage-2 reduce of P1 + BN1 fold: one block per output channel c
__global__ void k_finalize1(const float* __restrict__ p1, float* __restrict__ ws,
                            const float* __restrict__ gamma1, const float* __restrict__ beta1) {
    __shared__ float sm[2][4];
    const int c = blockIdx.x;           // 0..127
    const int t = threadIdx.x, l = t & 63, w = t >> 6;
    float s = 0.f, qq = 0.f;
#pragma unroll
    for (int r = t; r < NB1; r += 256) {
        s  += p1[(size_t)r * 256 + c];
        qq += p1[(size_t)r * 256 + 128 + c];
    }
#pragma unroll
    for (int off = 32; off; off >>= 1) { s += __shfl_xor(s, off, 64); qq += __shfl_xor(qq, off, 64); }
    if (l == 0) { sm[0][w] = s; sm[1][w] = qq; }
    __syncthreads();
    if (t == 0) {
        float S = sm[0][0] + sm[0][1] + sm[0][2] + sm[0][3];
        float Q = sm[1][0] + sm[1][1] + sm[1][2] + sm[1][3];
        float m = S * (1.f / NM);
        float var = Q * (1.f / NM) - m * m;
        float scale = gamma1[c] * rsqrtf(var + EPSBN);
        ws[WS_SCALE1 + c] = scale;
        ws[WS_SHIFT1 + c] = beta1[c] - m * scale;
    }
}

// 256 threads = 4 waves, grid-stride over voxels.
// Layer 0 on VALU (thread = channel x 16 points), z -> LDS bf16 [64][72]. Layer-1 GEMM
// on MFMA: y1(64p x 128o, K=128), K 0..63 = z, K 64..127 = broadcast agg (the concat,
// computed once per njl as dacc). W1 fragments in registers. Wave w owns cols 32w..32w+31.
// STATS: per-block partial sums/sumsqs -> pout[b][256] (no atomics). FINAL: BN1+ReLU+max
// -> out[n][128].
template <bool STATS>
__global__ __launch_bounds__(256) void k_pass(const float* __restrict__ x,
                                              const float* __restrict__ w0,
                                              const float* __restrict__ w1,
                                              const float* __restrict__ ws,
                                              float* __restrict__ pout) {
    __shared__ float xs[MPTS * CIN];              // 2560 B
    __shared__ unsigned short zB[MPTS * 72];      // 9216 B
    __shared__ unsigned short aggB[64];           // 128 B
    __shared__ float red[4 * 64];                 // 1024 B
    __shared__ float pbuf[256];                   // 1024 B (STATS partial staging)

    const int t  = threadIdx.x;
    const int l  = t & 63;
    const int w  = t >> 6;   // wave 0..3
    const int lr = l & 15;
    const int lg = l >> 4;

    // layer-0 role: channel ch for 16 points (quarter q)
    const int ch = t & 63;
    const int q  = t >> 6;
    float w0r[CIN];
#pragma unroll
    for (int i = 0; i < CIN; i++) w0r[i] = w0[ch * CIN + i];
    const float sc0 = ws[WS_SCALE0 + ch];
    const float sh0 = ws[WS_SHIFT0 + ch];

    // W1 register fragments: col = 32w+16njl+lr, k = 32ks+8lg+j
    bf16x8 wfrag[2][4];
#pragma unroll
    for (int njl = 0; njl < 2; njl++) {
        const float* wrow = w1 + (32 * w + 16 * njl + lr) * 128;
#pragma unroll
        for (int ks = 0; ks < 4; ks++) {
            float4 a = *(const float4*)(wrow + 32 * ks + 8 * lg);
            float4 b = *(const float4*)(wrow + 32 * ks + 8 * lg + 4);
            bf16x8 f;
            f[0] = (short)f2bf(a.x); f[1] = (short)f2bf(a.y);
            f[2] = (short)f2bf(a.z); f[3] = (short)f2bf(a.w);
            f[4] = (short)f2bf(b.x); f[5] = (short)f2bf(b.y);
            f[6] = (short)f2bf(b.z); f[7] = (short)f2bf(b.w);
            wfrag[njl][ks] = f;
        }
    }

    float sc1[2], sh1[2];
    if (!STATS) {
#pragma unroll
        for (int njl = 0; njl < 2; njl++) {
            int col = 32 * w + 16 * njl + lr;
            sc1[njl] = ws[WS_SCALE1 + col];
            sh1[njl] = ws[WS_SHIFT1 + col];
        }
    }
    float as_[2] = {0.f, 0.f}, aq[2] = {0.f, 0.f};

    const int nblk = STATS ? NB1 : NBF;
    for (int n = blockIdx.x; n < NVOX; n += nblk) {
        const float* xv = x + (size_t)n * (MPTS * CIN);
        if (t < 160) ((float4*)xs)[t] = ((const float4*)xv)[t];
        __syncthreads();

        // layer 0
        float pm = 0.f;
#pragma unroll
        for (int k = 0; k < 16; k++) {
            int p = q * 16 + k;
            const float* xp = xs + p * CIN;
            float y = xp[0] * w0r[0] + xp[1] * w0r[1] + xp[2] * w0r[2] + xp[3] * w0r[3] +
                      xp[4] * w0r[4] + xp[5] * w0r[5] + xp[6] * w0r[6] + xp[7] * w0r[7] +
                      xp[8] * w0r[8] + xp[9] * w0r[9];
            float v = fmaxf(fmaf(y, sc0, sh0), 0.f);
            zB[p * 72 + ch] = f2bf(v);
            pm = fmaxf(pm, v);
        }
        red[q * 64 + ch] = pm;
        __syncthreads();
        if (t < 64) {
            float m = fmaxf(fmaxf(red[t], red[64 + t]), fmaxf(red[128 + t], red[192 + t]));
            aggB[t] = f2bf(m);
        }
        __syncthreads();

        // MFMA GEMM
        bf16x8 afrag[4][2];
#pragma unroll
        for (int mi = 0; mi < 4; mi++)
#pragma unroll
            for (int ks = 0; ks < 2; ks++)
                afrag[mi][ks] = *(const bf16x8*)&zB[(16 * mi + lr) * 72 + 32 * ks + 8 * lg];
        bf16x8 gfrag[2];
#pragma unroll
        for (int ksh = 0; ksh < 2; ksh++)
            gfrag[ksh] = *(const bf16x8*)&aggB[32 * ksh + 8 * lg];

        f32x4 dacc[2];
#pragma unroll
        for (int njl = 0; njl < 2; njl++) {
            f32x4 zz = {0.f, 0.f, 0.f, 0.f};
            zz = __builtin_amdgcn_mfma_f32_16x16x32_bf16(gfrag[0], wfrag[njl][2], zz, 0, 0, 0);
            dacc[njl] = __builtin_amdgcn_mfma_f32_16x16x32_bf16(gfrag[1], wfrag[njl][3], zz, 0, 0, 0);
        }

        float vm[2] = {0.f, 0.f};
#pragma unroll
        for (int njl = 0; njl < 2; njl++) {
#pragma unroll
            for (int mi = 0; mi < 4; mi++) {
                f32x4 acc = dacc[njl];
                acc = __builtin_amdgcn_mfma_f32_16x16x32_bf16(afrag[mi][0], wfrag[njl][0], acc, 0, 0, 0);
                acc = __builtin_amdgcn_mfma_f32_16x16x32_bf16(afrag[mi][1], wfrag[njl][1], acc, 0, 0, 0);
                if (STATS) {
#pragma unroll
                    for (int r = 0; r < 4; r++) { as_[njl] += acc[r]; aq[njl] += acc[r] * acc[r]; }
                } else {
#pragma unroll
                    for (int r = 0; r < 4; r++)
                        vm[njl] = fmaxf(vm[njl], fmaxf(fmaf(acc[r], sc1[njl], sh1[njl]), 0.f));
                }
            }
        }

        if (!STATS) {
#pragma unroll
            for (int njl = 0; njl < 2; njl++) {
                float v = vm[njl];
                v = fmaxf(v, __shfl_xor(v, 16));
                v = fmaxf(v, __shfl_xor(v, 32));
                if (l < 16) pout[(size_t)n * 128 + 32 * w + 16 * njl + l] = v;
            }
        }
    }

    if (STATS) {
        // per-wave reduce, stage in LDS, one coalesced 1 KB partial store per block
#pragma unroll
        for (int njl = 0; njl < 2; njl++) {
            float s = as_[njl];
            s += __shfl_xor(s, 16); s += __shfl_xor(s, 32);
            float qq = aq[njl];
            qq += __shfl_xor(qq, 16); qq += __shfl_xor(qq, 32);
            if (l < 16) {
                int col = 32 * w + 16 * njl + l;
                pbuf[col] = s;
                pbuf[128 + col] = qq;
            }
        }
        __syncthreads();
        pout[(size_t)blockIdx.x * 256 + t] = pbuf[t];
    }
}

extern "C" void kernel_launch(void* const* d_in, const int* in_sizes, int n_in,
                              void* d_out, int out_size, void* d_ws, size_t ws_size,
                              hipStream_t stream) {
    (void)in_sizes; (void)n_in; (void)out_size; (void)ws_size;
    const float* x      = (const float*)d_in[0];
    const float* W0     = (const float*)d_in[1];
    const float* gamma0 = (const float*)d_in[2];
    const float* beta0  = (const float*)d_in[3];
    const float* W1     = (const float*)d_in[4];
    const float* gamma1 = (const float*)d_in[5];
    const float* beta1  = (const float*)d_in[6];
    float* out = (float*)d_out;
    float* ws  = (float*)d_ws;

    k_stats0<<<NB0, 256, 0, stream>>>(x, out);                       // partials -> out
    k_finalize0<<<1, 256, 0, stream>>>(out, ws, W0, gamma0, beta0);
    k_pass<true><<<NB1, 256, 0, stream>>>(x, W0, W1, ws, out);       // partials -> out
    k_finalize1<<<128, 256, 0, stream>>>(out, ws, gamma1, beta1);
    k_pass<false><<<NBF, 256, 0, stream>>>(x, W0, W1, ws, out);      // final output
}

// Round 4
// 242.786 us; speedup vs baseline: 6.7156x; 1.0051x over previous
//
#include <hip/hip_runtime.h>

#define NVOX 20000
#define MPTS 64
#define CIN  10
#define NM   (NVOX*MPTS)      // 1,280,000
#define EPSBN 1e-3f

// ws param layout (float offsets) — only 512 floats used
#define WS_SCALE0 0     // 64
#define WS_SHIFT0 64    // 64
#define WS_SCALE1 128   // 128
#define WS_SHIFT1 256   // 128

// d_out doubles as stream-ordered scratch for reduction partials.
#define NB0   512       // stats0 blocks -> P0 partials [NB0][P0STR]
#define P0STR 72
#define NB1   2000      // pass<true> blocks -> P1 partials [NB1][256]
#define NBF   2000      // pass<false> blocks (10 voxels each)

typedef short bf16x8 __attribute__((ext_vector_type(8)));
typedef float f32x4  __attribute__((ext_vector_type(4)));
typedef unsigned int u32x4 __attribute__((ext_vector_type(4)));

__device__ __forceinline__ unsigned short f2bf(float f) {
    union { float f; unsigned u; } v; v.f = f;
    unsigned r = v.u + 0x7FFFu + ((v.u >> 16) & 1u);   // RNE to bf16
    return (unsigned short)(r >> 16);
}
// HW packed f32x2 -> bf16x2 (no builtin on gfx950; m240)
__device__ __forceinline__ unsigned cvtpk(float lo, float hi) {
    unsigned d;
    asm("v_cvt_pk_bf16_f32 %0, %1, %2" : "=v"(d) : "v"(lo), "v"(hi));
    return d;
}
// packed u16 max: valid max for ReLU'd (non-negative) bf16 bit patterns
__device__ __forceinline__ unsigned pkmax(unsigned a, unsigned b) {
    unsigned d;
    asm("v_pk_max_u16 %0, %1, %2" : "=v"(d) : "v"(a), "v"(b));
    return d;
}

// x-moment pass: Sx (10) + Sxx (55 packed) via per-block partials, NO atomics.
__global__ __launch_bounds__(256) void k_stats0(const float* __restrict__ x,
                                                float* __restrict__ p0) {
    __shared__ float sm[4][P0STR];
    float sx[CIN];
    float sxx[55];
#pragma unroll
    for (int i = 0; i < CIN; i++) sx[i] = 0.f;
#pragma unroll
    for (int k = 0; k < 55; k++) sxx[k] = 0.f;

    const int t = threadIdx.x;
    const int tid = blockIdx.x * 256 + t;

    for (int g = tid; g < NM / 2; g += NB0 * 256) {
        const float4* xp = (const float4*)(x + (size_t)g * 20);
        float4 a = xp[0], b = xp[1], c = xp[2], d = xp[3], e = xp[4];
        float v0[CIN] = {a.x, a.y, a.z, a.w, b.x, b.y, b.z, b.w, c.x, c.y};
        float v1[CIN] = {c.z, c.w, d.x, d.y, d.z, d.w, e.x, e.y, e.z, e.w};
#pragma unroll
        for (int i = 0; i < CIN; i++) sx[i] += v0[i] + v1[i];
#pragma unroll
        for (int i = 0; i < CIN; i++)
#pragma unroll
            for (int j = 0; j <= i; j++)
                sxx[i * (i + 1) / 2 + j] += v0[i] * v0[j] + v1[i] * v1[j];
    }

    const int l = t & 63, w = t >> 6;
#pragma unroll
    for (int i = 0; i < CIN; i++) {
        float v = sx[i];
#pragma unroll
        for (int off = 32; off; off >>= 1) v += __shfl_xor(v, off, 64);
        if (l == 0) sm[w][i] = v;
    }
#pragma unroll
    for (int k = 0; k < 55; k++) {
        float v = sxx[k];
#pragma unroll
        for (int off = 32; off; off >>= 1) v += __shfl_xor(v, off, 64);
        if (l == 0) sm[w][10 + k] = v;
    }
    __syncthreads();
    if (t < 65)
        p0[blockIdx.x * P0STR + t] = sm[0][t] + sm[1][t] + sm[2][t] + sm[3][t];
}

__global__ void k_finalize0(const float* __restrict__ p0, float* __restrict__ ws,
                            const float* __restrict__ w0,
                            const float* __restrict__ gamma0, const float* __restrict__ beta0) {
    __shared__ float s[P0STR];
    const int t = threadIdx.x;
    if (t < 65) {
        float acc = 0.f;
#pragma unroll 8
        for (int r = 0; r < NB0; r++) acc += p0[r * P0STR + t];
        s[t] = acc;
    }
    __syncthreads();
    if (t < 64) {
        float w[CIN];
#pragma unroll
        for (int i = 0; i < CIN; i++) w[i] = w0[t * CIN + i];
        float m = 0.f;
#pragma unroll
        for (int i = 0; i < CIN; i++) m += w[i] * s[i];
        m *= (1.f / NM);
        float q = 0.f;
#pragma unroll
        for (int i = 0; i < CIN; i++)
#pragma unroll
            for (int j = 0; j <= i; j++)
                q += ((i == j) ? 1.f : 2.f) * w[i] * w[j] * s[10 + i * (i + 1) / 2 + j];
        q *= (1.f / NM);
        float var = q - m * m;
        float scale = gamma0[t] * rsqrtf(var + EPSBN);
        ws[WS_SCALE0 + t] = scale;
        ws[WS_SHIFT0 + t] = beta0[t] - m * scale;
    }
}

__global__ void k_finalize1(const float* __restrict__ p1, float* __restrict__ ws,
                            const float* __restrict__ gamma1, const float* __restrict__ beta1) {
    __shared__ float sm[2][4];
    const int c = blockIdx.x;
    const int t = threadIdx.x, l = t & 63, w = t >> 6;
    float s = 0.f, qq = 0.f;
    for (int r = t; r < NB1; r += 256) {
        s  += p1[(size_t)r * 256 + c];
        qq += p1[(size_t)r * 256 + 128 + c];
    }
#pragma unroll
    for (int off = 32; off; off >>= 1) { s += __shfl_xor(s, off, 64); qq += __shfl_xor(qq, off, 64); }
    if (l == 0) { sm[0][w] = s; sm[1][w] = qq; }
    __syncthreads();
    if (t == 0) {
        float S = sm[0][0] + sm[0][1] + sm[0][2] + sm[0][3];
        float Q = sm[1][0] + sm[1][1] + sm[1][2] + sm[1][3];
        float m = S * (1.f / NM);
        float var = Q * (1.f / NM) - m * m;
        float scale = gamma1[c] * rsqrtf(var + EPSBN);
        ws[WS_SCALE1 + c] = scale;
        ws[WS_SHIFT1 + c] = beta1[c] - m * scale;
    }
}

// 256 threads = 4 waves, 10 voxels per block.
// Layer 0 on MFMA: C0[ch][p] = (sc0*W0 | sh0) . (x | 1)^T, K=10+1 padded to 32.
//   Wave w owns p-cols 16w..16w+15; lane holds col p=16w+lr, rows ch=16mi+4lg+r ->
//   4 consecutive ch = one packed b64 write into row-major zB[p][ch] (chunk16 XOR-swizzled).
// agg[ch] = max_p z: packed v_pk_max_u16 (valid for ReLU'd bf16) — 2 row-reads +
//   3-stage butterfly per wave -> aggP[w][64]; 4-way fold happens in the gfrag load.
// Layer 1 on MFMA (R2 structure): y1[p][o], K 0..63 = zB rows, K 64..127 = broadcast agg.
// 3 barriers/voxel.
template <bool STATS>
__global__ __launch_bounds__(256) void k_pass(const float* __restrict__ x,
                                              const float* __restrict__ w0,
                                              const float* __restrict__ w1,
                                              const float* __restrict__ ws,
                                              float* __restrict__ pout) {
    __shared__ unsigned short xB[MPTS * 40];   // 5120 B  (k0..9 data, k10=1.0, k11..31=0)
    __shared__ unsigned short zB[MPTS * 72];   // 9216 B  (row-major [p][ch], swizzled chunks)
    __shared__ unsigned short aggP[4 * 64];    // 512 B   (per-wave agg partials, bf16)
    __shared__ float pbuf[256];                // STATS partial staging

    const int t  = threadIdx.x;
    const int l  = t & 63;
    const int w  = t >> 6;
    const int lr = l & 15;
    const int lg = l >> 4;

    // ---- init xB constant region (once per block) ----
    for (int i = t; i < MPTS * 40 / 2; i += 256) ((unsigned*)xB)[i] = 0u;
    __syncthreads();
    if (t < 64) xB[t * 40 + 10] = 0x3F80;      // the "+shift" ones-column

    // ---- W0 fragments, BN0 folded: rows ch = 16mi+lr, k = 8lg+j ----
    bf16x8 w0f[4];
#pragma unroll
    for (int mi = 0; mi < 4; mi++) {
        int ch = 16 * mi + lr;
        float sc = ws[WS_SCALE0 + ch], sh = ws[WS_SHIFT0 + ch];
        bf16x8 f;
#pragma unroll
        for (int j = 0; j < 8; j++) {
            int k = 8 * lg + j;
            float v = (k < CIN) ? sc * w0[ch * CIN + k] : (k == CIN ? sh : 0.f);
            f[j] = (short)f2bf(v);
        }
        w0f[mi] = f;
    }

    // ---- W1 fragments: rows o = 32w+16njl+lr, k = 32ks+8lg+j ----
    bf16x8 wfrag[2][4];
#pragma unroll
    for (int njl = 0; njl < 2; njl++) {
        const float* wrow = w1 + (32 * w + 16 * njl + lr) * 128;
#pragma unroll
        for (int ks = 0; ks < 4; ks++) {
            float4 a = *(const float4*)(wrow + 32 * ks + 8 * lg);
            float4 b = *(const float4*)(wrow + 32 * ks + 8 * lg + 4);
            bf16x8 f;
            f[0] = (short)f2bf(a.x); f[1] = (short)f2bf(a.y);
            f[2] = (short)f2bf(a.z); f[3] = (short)f2bf(a.w);
            f[4] = (short)f2bf(b.x); f[5] = (short)f2bf(b.y);
            f[6] = (short)f2bf(b.z); f[7] = (short)f2bf(b.w);
            wfrag[njl][ks] = f;
        }
    }

    float sc1[2], sh1[2];
    if (!STATS) {
#pragma unroll
        for (int njl = 0; njl < 2; njl++) {
            int col = 32 * w + 16 * njl + lr;
            sc1[njl] = ws[WS_SCALE1 + col];
            sh1[njl] = ws[WS_SHIFT1 + col];
        }
    }
    float as_[2] = {0.f, 0.f}, aq[2] = {0.f, 0.f};

    const int nblk = STATS ? NB1 : NBF;
    for (int n = blockIdx.x; n < NVOX; n += nblk) {
        // ---- stage x -> bf16 xB (t<128: thread = (point, half-row)) ----
        if (t < 128) {
            int p = t >> 1, h = t & 1;
            const float* xp = x + (size_t)n * (MPTS * CIN) + p * CIN;
            if (h == 0) {                      // k0..3
                float2 a = ((const float2*)xp)[0];
                float2 b = ((const float2*)xp)[1];
                uint2 d = { cvtpk(a.x, a.y), cvtpk(b.x, b.y) };
                *(uint2*)&xB[p * 40] = d;
            } else {                           // k4..9
                float2 a = ((const float2*)(xp + 4))[0];
                float2 b = ((const float2*)(xp + 4))[1];
                float2 c = ((const float2*)(xp + 4))[2];
                uint2 d = { cvtpk(a.x, a.y), cvtpk(b.x, b.y) };
                *(uint2*)&xB[p * 40 + 4] = d;
                *(unsigned*)&xB[p * 40 + 8] = cvtpk(c.x, c.y);
            }
        }
        __syncthreads();   // B1: xB ready

        // ---- layer 0: 4 MFMA + ReLU + packed zB write ----
        {
            const int p = 16 * w + lr;
            bf16x8 bx = *(const bf16x8*)&xB[p * 40 + 8 * lg];
#pragma unroll
            for (int mi = 0; mi < 4; mi++) {
                f32x4 zz = {0.f, 0.f, 0.f, 0.f};
                f32x4 a0 = __builtin_amdgcn_mfma_f32_16x16x32_bf16(w0f[mi], bx, zz, 0, 0, 0);
                unsigned d0 = cvtpk(fmaxf(a0[0], 0.f), fmaxf(a0[1], 0.f));
                unsigned d1 = cvtpk(fmaxf(a0[2], 0.f), fmaxf(a0[3], 0.f));
                int chunk = 2 * mi + (lg >> 1);
                int idx = p * 72 + ((chunk ^ (p & 7)) << 3) + ((lg & 1) << 2);
                uint2 dd = {d0, d1};
                *(uint2*)&zB[idx] = dd;
            }
        }
        __syncthreads();   // B2: zB ready

        // ---- agg partials: per-wave max over its 16 p-rows, packed bf16 ----
        {
            int cs = t & 7;
            int pa = (t >> 3) * 2, pb = pa + 1;
            u32x4 ra = *(const u32x4*)&zB[pa * 72 + ((cs ^ (pa & 7)) << 3)];
            u32x4 rb = *(const u32x4*)&zB[pb * 72 + ((cs ^ (pb & 7)) << 3)];
            u32x4 m;
#pragma unroll
            for (int k2 = 0; k2 < 4; k2++) m[k2] = pkmax(ra[k2], rb[k2]);
#pragma unroll
            for (int off = 8; off <= 32; off <<= 1)
#pragma unroll
                for (int k2 = 0; k2 < 4; k2++) m[k2] = pkmax(m[k2], __shfl_xor(m[k2], off));
            if (l < 8) *(u32x4*)&aggP[w * 64 + l * 8] = m;
        }
        __syncthreads();   // B3: aggP ready

        // ---- layer-1 fragments ----
        bf16x8 bz[4][2];
#pragma unroll
        for (int pj = 0; pj < 4; pj++) {
            int p = 16 * pj + lr;
#pragma unroll
            for (int ks = 0; ks < 2; ks++)
                bz[pj][ks] = *(const bf16x8*)&zB[p * 72 + (((4 * ks + lg) ^ (p & 7)) << 3)];
        }
        bf16x8 gfrag[2];
#pragma unroll
        for (int ks = 0; ks < 2; ks++) {
            int sl = (4 * ks + lg) * 8;
            u32x4 g = *(const u32x4*)&aggP[sl];
#pragma unroll
            for (int wv = 1; wv < 4; wv++) {
                u32x4 h2 = *(const u32x4*)&aggP[wv * 64 + sl];
#pragma unroll
                for (int k2 = 0; k2 < 4; k2++) g[k2] = pkmax(g[k2], h2[k2]);
            }
            gfrag[ks] = __builtin_bit_cast(bf16x8, g);
        }

        // ---- layer-1 GEMM (R2 structure) ----
        f32x4 dacc[2];
#pragma unroll
        for (int njl = 0; njl < 2; njl++) {
            f32x4 zz = {0.f, 0.f, 0.f, 0.f};
            zz = __builtin_amdgcn_mfma_f32_16x16x32_bf16(gfrag[0], wfrag[njl][2], zz, 0, 0, 0);
            dacc[njl] = __builtin_amdgcn_mfma_f32_16x16x32_bf16(gfrag[1], wfrag[njl][3], zz, 0, 0, 0);
        }

        float vm[2] = {0.f, 0.f};
#pragma unroll
        for (int njl = 0; njl < 2; njl++) {
#pragma unroll
            for (int mi = 0; mi < 4; mi++) {
                f32x4 acc = dacc[njl];
                acc = __builtin_amdgcn_mfma_f32_16x16x32_bf16(bz[mi][0], wfrag[njl][0], acc, 0, 0, 0);
                acc = __builtin_amdgcn_mfma_f32_16x16x32_bf16(bz[mi][1], wfrag[njl][1], acc, 0, 0, 0);
                if (STATS) {
#pragma unroll
                    for (int r = 0; r < 4; r++) { as_[njl] += acc[r]; aq[njl] += acc[r] * acc[r]; }
                } else {
#pragma unroll
                    for (int r = 0; r < 4; r++)
                        vm[njl] = fmaxf(vm[njl], fmaxf(fmaf(acc[r], sc1[njl], sh1[njl]), 0.f));
                }
            }
        }

        if (!STATS) {
#pragma unroll
            for (int njl = 0; njl < 2; njl++) {
                float v = vm[njl];
                v = fmaxf(v, __shfl_xor(v, 16));
                v = fmaxf(v, __shfl_xor(v, 32));
                if (l < 16) pout[(size_t)n * 128 + 32 * w + 16 * njl + l] = v;
            }
        }
    }

    if (STATS) {
#pragma unroll
        for (int njl = 0; njl < 2; njl++) {
            float s = as_[njl];
            s += __shfl_xor(s, 16); s += __shfl_xor(s, 32);
            float qq = aq[njl];
            qq += __shfl_xor(qq, 16); qq += __shfl_xor(qq, 32);
            if (l < 16) {
                int col = 32 * w + 16 * njl + l;
                pbuf[col] = s;
                pbuf[128 + col] = qq;
            }
        }
        __syncthreads();
        pout[(size_t)blockIdx.x * 256 + t] = pbuf[t];
    }
}

extern "C" void kernel_launch(void* const* d_in, const int* in_sizes, int n_in,
                              void* d_out, int out_size, void* d_ws, size_t ws_size,
                              hipStream_t stream) {
    (void)in_sizes; (void)n_in; (void)out_size; (void)ws_size;
    const float* x      = (const float*)d_in[0];
    const float* W0     = (const float*)d_in[1];
    const float* gamma0 = (const float*)d_in[2];
    const float* beta0  = (const float*)d_in[3];
    const float* W1     = (const float*)d_in[4];
    const float* gamma1 = (const float*)d_in[5];
    const float* beta1  = (const float*)d_in[6];
    float* out = (float*)d_out;
    float* ws  = (float*)d_ws;

    k_stats0<<<NB0, 256, 0, stream>>>(x, out);                       // partials -> out
    k_finalize0<<<1, 256, 0, stream>>>(out, ws, W0, gamma0, beta0);
    k_pass<true><<<NB1, 256, 0, stream>>>(x, W0, W1, ws, out);       // partials -> out
    k_finalize1<<<128, 256, 0, stream>>>(out, ws, gamma1, beta1);
    k_pass<false><<<NBF, 256, 0, stream>>>(x, W0, W1, ws, out);      // final output
}

// Round 5
// 220.936 us; speedup vs baseline: 7.3797x; 1.0989x over previous
//
#include <hip/hip_runtime.h>

#define NVOX 20000
#define MPTS 64
#define CIN  10
#define NM   (NVOX*MPTS)      // 1,280,000
#define EPSBN 1e-3f

// ws param layout (float offsets) — only 512 floats used
#define WS_SCALE0 0     // 64
#define WS_SHIFT0 64    // 64
#define WS_SCALE1 128   // 128
#define WS_SHIFT1 256   // 128

// d_out doubles as stream-ordered scratch for reduction partials.
#define NB0   512       // stats0 blocks -> P0 partials [NB0][P0STR]
#define P0STR 72
#define NB1   2000      // pass<true> blocks -> P1 partials [NB1][256]
#define NBF   2000      // pass<false> blocks (10 voxels each)

typedef short bf16x8 __attribute__((ext_vector_type(8)));
typedef float f32x4  __attribute__((ext_vector_type(4)));
typedef unsigned int u32x4 __attribute__((ext_vector_type(4)));

__device__ __forceinline__ unsigned short f2bf(float f) {
    union { float f; unsigned u; } v; v.f = f;
    unsigned r = v.u + 0x7FFFu + ((v.u >> 16) & 1u);   // RNE to bf16
    return (unsigned short)(r >> 16);
}
// HW packed f32x2 -> bf16x2 (no builtin on gfx950; m240)
__device__ __forceinline__ unsigned cvtpk(float lo, float hi) {
    unsigned d;
    asm("v_cvt_pk_bf16_f32 %0, %1, %2" : "=v"(d) : "v"(lo), "v"(hi));
    return d;
}
// packed u16 max: valid max for ReLU'd (non-negative) bf16 bit patterns
__device__ __forceinline__ unsigned pkmax(unsigned a, unsigned b) {
    unsigned d;
    asm("v_pk_max_u16 %0, %1, %2" : "=v"(d) : "v"(a), "v"(b));
    return d;
}

// x-moment pass: Sx (10) + Sxx (55 packed) via per-block partials, NO atomics.
__global__ __launch_bounds__(256) void k_stats0(const float* __restrict__ x,
                                                float* __restrict__ p0) {
    __shared__ float sm[4][P0STR];
    float sx[CIN];
    float sxx[55];
#pragma unroll
    for (int i = 0; i < CIN; i++) sx[i] = 0.f;
#pragma unroll
    for (int k = 0; k < 55; k++) sxx[k] = 0.f;

    const int t = threadIdx.x;
    const int tid = blockIdx.x * 256 + t;

    for (int g = tid; g < NM / 2; g += NB0 * 256) {
        const float4* xp = (const float4*)(x + (size_t)g * 20);
        float4 a = xp[0], b = xp[1], c = xp[2], d = xp[3], e = xp[4];
        float v0[CIN] = {a.x, a.y, a.z, a.w, b.x, b.y, b.z, b.w, c.x, c.y};
        float v1[CIN] = {c.z, c.w, d.x, d.y, d.z, d.w, e.x, e.y, e.z, e.w};
#pragma unroll
        for (int i = 0; i < CIN; i++) sx[i] += v0[i] + v1[i];
#pragma unroll
        for (int i = 0; i < CIN; i++)
#pragma unroll
            for (int j = 0; j <= i; j++)
                sxx[i * (i + 1) / 2 + j] += v0[i] * v0[j] + v1[i] * v1[j];
    }

    const int l = t & 63, w = t >> 6;
#pragma unroll
    for (int i = 0; i < CIN; i++) {
        float v = sx[i];
#pragma unroll
        for (int off = 32; off; off >>= 1) v += __shfl_xor(v, off, 64);
        if (l == 0) sm[w][i] = v;
    }
#pragma unroll
    for (int k = 0; k < 55; k++) {
        float v = sxx[k];
#pragma unroll
        for (int off = 32; off; off >>= 1) v += __shfl_xor(v, off, 64);
        if (l == 0) sm[w][10 + k] = v;
    }
    __syncthreads();
    if (t < 65)
        p0[blockIdx.x * P0STR + t] = sm[0][t] + sm[1][t] + sm[2][t] + sm[3][t];
}

__global__ void k_finalize0(const float* __restrict__ p0, float* __restrict__ ws,
                            const float* __restrict__ w0,
                            const float* __restrict__ gamma0, const float* __restrict__ beta0) {
    __shared__ float s[P0STR];
    const int t = threadIdx.x;
    if (t < 65) {
        float acc = 0.f;
#pragma unroll 8
        for (int r = 0; r < NB0; r++) acc += p0[r * P0STR + t];
        s[t] = acc;
    }
    __syncthreads();
    if (t < 64) {
        float w[CIN];
#pragma unroll
        for (int i = 0; i < CIN; i++) w[i] = w0[t * CIN + i];
        float m = 0.f;
#pragma unroll
        for (int i = 0; i < CIN; i++) m += w[i] * s[i];
        m *= (1.f / NM);
        float q = 0.f;
#pragma unroll
        for (int i = 0; i < CIN; i++)
#pragma unroll
            for (int j = 0; j <= i; j++)
                q += ((i == j) ? 1.f : 2.f) * w[i] * w[j] * s[10 + i * (i + 1) / 2 + j];
        q *= (1.f / NM);
        float var = q - m * m;
        float scale = gamma0[t] * rsqrtf(var + EPSBN);
        ws[WS_SCALE0 + t] = scale;
        ws[WS_SHIFT0 + t] = beta0[t] - m * scale;
    }
}

__global__ void k_finalize1(const float* __restrict__ p1, float* __restrict__ ws,
                            const float* __restrict__ gamma1, const float* __restrict__ beta1) {
    __shared__ float sm[2][4];
    const int c = blockIdx.x;
    const int t = threadIdx.x, l = t & 63, w = t >> 6;
    float s = 0.f, qq = 0.f;
    for (int r = t; r < NB1; r += 256) {
        s  += p1[(size_t)r * 256 + c];
        qq += p1[(size_t)r * 256 + 128 + c];
    }
#pragma unroll
    for (int off = 32; off; off >>= 1) { s += __shfl_xor(s, off, 64); qq += __shfl_xor(qq, off, 64); }
    if (l == 0) { sm[0][w] = s; sm[1][w] = qq; }
    __syncthreads();
    if (t == 0) {
        float S = sm[0][0] + sm[0][1] + sm[0][2] + sm[0][3];
        float Q = sm[1][0] + sm[1][1] + sm[1][2] + sm[1][3];
        float m = S * (1.f / NM);
        float var = Q * (1.f / NM) - m * m;
        float scale = gamma1[c] * rsqrtf(var + EPSBN);
        ws[WS_SCALE1 + c] = scale;
        ws[WS_SHIFT1 + c] = beta1[c] - m * scale;
    }
}

// 256 threads = 4 waves, 10 voxels per block, software-pipelined.
// xB is WAVE-PRIVATE (wave w stages+reads rows 16w..16w+15): prefetch x(n+1) into regs
// at iter top, commit to LDS next iter — no barrier, latency hidden a full iteration.
// zB [p][ch] stride 72 shorts (144 B = 9 slots): the odd 16B-slot count gives a natural
// per-row rotation slot=(p+c)%8 — conflict-free per 8-lane beat WITHOUT any swizzle.
// agg partials are wave-local (wave reads exactly the zB rows it wrote; DS is in-order
// per wave) -> only 2 barriers/voxel, both raw s_barrier + lgkmcnt-only drain so the
// x prefetch stays in flight across them.
template <bool STATS>
__global__ __launch_bounds__(256) void k_pass(const float* __restrict__ x,
                                              const float* __restrict__ w0,
                                              const float* __restrict__ w1,
                                              const float* __restrict__ ws,
                                              float* __restrict__ pout) {
    __shared__ unsigned short xB[MPTS * 40];   // 5120 B  (k0..9 data, k10=1.0, rest 0)
    __shared__ unsigned short zB[MPTS * 72];   // 9216 B  ([p][ch], natural rotation)
    __shared__ unsigned short aggP[4 * 64];    // 512 B
    __shared__ float pbuf[256];                // STATS partial staging

    const int t  = threadIdx.x;
    const int l  = t & 63;
    const int w  = t >> 6;
    const int lr = l & 15;
    const int lg = l >> 4;
    const int srow = 16 * w + (l >> 2);   // stage: this wave's own xB row
    const int ssub = l & 3;               // stage: 0:k0-3, 1:k4-7, 2:k8-9, 3:idle
    const int prow = 16 * w + lr;         // L0: this lane's point column

    // once-per-block xB constant region
    for (int i = t; i < MPTS * 40 / 2; i += 256) ((unsigned*)xB)[i] = 0u;
    __syncthreads();
    if (t < 64) xB[t * 40 + 10] = 0x3F80;  // the "+shift" ones-column

    // W0 fragments, BN0 folded: rows ch = 16mi+lr, k = 8lg+j
    bf16x8 w0f[4];
#pragma unroll
    for (int mi = 0; mi < 4; mi++) {
        int ch = 16 * mi + lr;
        float sc = ws[WS_SCALE0 + ch], sh = ws[WS_SHIFT0 + ch];
        bf16x8 f;
#pragma unroll
        for (int j = 0; j < 8; j++) {
            int k = 8 * lg + j;
            float v = (k < CIN) ? sc * w0[ch * CIN + k] : (k == CIN ? sh : 0.f);
            f[j] = (short)f2bf(v);
        }
        w0f[mi] = f;
    }

    // W1 fragments: rows o = 32w+16njl+lr, k = 32ks+8lg+j
    bf16x8 wfrag[2][4];
#pragma unroll
    for (int njl = 0; njl < 2; njl++) {
        const float* wrow = w1 + (32 * w + 16 * njl + lr) * 128;
#pragma unroll
        for (int ks = 0; ks < 4; ks++) {
            float4 a = *(const float4*)(wrow + 32 * ks + 8 * lg);
            float4 b = *(const float4*)(wrow + 32 * ks + 8 * lg + 4);
            bf16x8 f;
            f[0] = (short)f2bf(a.x); f[1] = (short)f2bf(a.y);
            f[2] = (short)f2bf(a.z); f[3] = (short)f2bf(a.w);
            f[4] = (short)f2bf(b.x); f[5] = (short)f2bf(b.y);
            f[6] = (short)f2bf(b.z); f[7] = (short)f2bf(b.w);
            wfrag[njl][ks] = f;
        }
    }

    float sc1[2], sh1[2];
    if (!STATS) {
#pragma unroll
        for (int njl = 0; njl < 2; njl++) {
            int col = 32 * w + 16 * njl + lr;
            sc1[njl] = ws[WS_SCALE1 + col];
            sh1[njl] = ws[WS_SHIFT1 + col];
        }
    }
    float as_[2] = {0.f, 0.f}, aq[2] = {0.f, 0.f};

    __syncthreads();   // k10 writes (wave 0) visible before any L0 read

    // prologue: prefetch first voxel's x into regs
    float2 pfa, pfb;
    {
        const float* xr = x + (size_t)blockIdx.x * 640 + srow * 10;
        if (ssub < 2) { pfa = *(const float2*)(xr + ssub * 4); pfb = *(const float2*)(xr + ssub * 4 + 2); }
        else if (ssub == 2) { pfa = *(const float2*)(xr + 8); }
    }

    const int nblk = STATS ? NB1 : NBF;
    for (int n = blockIdx.x; n < NVOX; n += nblk) {
        // ---- commit xB(n) from prefetch regs (wave-private; no barrier) ----
        if (ssub < 2) {
            uint2 d = { cvtpk(pfa.x, pfa.y), cvtpk(pfb.x, pfb.y) };
            *(uint2*)&xB[srow * 40 + ssub * 4] = d;
        } else if (ssub == 2) {
            *(unsigned*)&xB[srow * 40 + 8] = cvtpk(pfa.x, pfa.y);
        }
        // ---- issue prefetch for voxel n+nblk ----
        {
            int nn = n + nblk;
            if (nn < NVOX) {
                const float* xr = x + (size_t)nn * 640 + srow * 10;
                if (ssub < 2) { pfa = *(const float2*)(xr + ssub * 4); pfb = *(const float2*)(xr + ssub * 4 + 2); }
                else if (ssub == 2) { pfa = *(const float2*)(xr + 8); }
            }
        }

        // ---- layer 0: 4 MFMA + ReLU + packed zB write (rows prow = wave-own) ----
        {
            bf16x8 bx = *(const bf16x8*)&xB[prow * 40 + 8 * lg];
#pragma unroll
            for (int mi = 0; mi < 4; mi++) {
                f32x4 zz = {0.f, 0.f, 0.f, 0.f};
                f32x4 a0 = __builtin_amdgcn_mfma_f32_16x16x32_bf16(w0f[mi], bx, zz, 0, 0, 0);
                uint2 dd = { cvtpk(fmaxf(a0[0], 0.f), fmaxf(a0[1], 0.f)),
                             cvtpk(fmaxf(a0[2], 0.f), fmaxf(a0[3], 0.f)) };
                *(uint2*)&zB[prow * 72 + 16 * mi + 4 * lg] = dd;
            }
        }

        // ---- agg partials: wave-local max over own 16 zB rows (DS in-order per wave) ----
        {
            int cs = l & 7;
            int pa = 16 * w + 2 * (l >> 3);
            u32x4 ra = *(const u32x4*)&zB[pa * 72 + cs * 8];
            u32x4 rb = *(const u32x4*)&zB[(pa + 1) * 72 + cs * 8];
            u32x4 m;
#pragma unroll
            for (int k2 = 0; k2 < 4; k2++) m[k2] = pkmax(ra[k2], rb[k2]);
#pragma unroll
            for (int off = 8; off <= 32; off <<= 1)
#pragma unroll
                for (int k2 = 0; k2 < 4; k2++) m[k2] = pkmax(m[k2], __shfl_xor(m[k2], off));
            if (l < 8) *(u32x4*)&aggP[w * 64 + l * 8] = m;
        }

        asm volatile("s_waitcnt lgkmcnt(0)" ::: "memory");
        __builtin_amdgcn_s_barrier();          // B_a: zB + aggP globally ready

        // ---- layer-1 fragments ----
        bf16x8 bz[4][2];
#pragma unroll
        for (int pj = 0; pj < 4; pj++) {
            int p = 16 * pj + lr;
#pragma unroll
            for (int ks = 0; ks < 2; ks++)
                bz[pj][ks] = *(const bf16x8*)&zB[p * 72 + (4 * ks + lg) * 8];
        }
        bf16x8 gfrag[2];
#pragma unroll
        for (int ks = 0; ks < 2; ks++) {
            int sl = (4 * ks + lg) * 8;
            u32x4 g = *(const u32x4*)&aggP[sl];
#pragma unroll
            for (int wv = 1; wv < 4; wv++) {
                u32x4 h2 = *(const u32x4*)&aggP[wv * 64 + sl];
#pragma unroll
                for (int k2 = 0; k2 < 4; k2++) g[k2] = pkmax(g[k2], h2[k2]);
            }
            gfrag[ks] = __builtin_bit_cast(bf16x8, g);
        }

        asm volatile("s_waitcnt lgkmcnt(0)" ::: "memory");
        __builtin_amdgcn_s_barrier();          // B_b: fragments landed; zB/aggP free

        // ---- layer-1 GEMM ----
        f32x4 dacc[2];
#pragma unroll
        for (int njl = 0; njl < 2; njl++) {
            f32x4 zz = {0.f, 0.f, 0.f, 0.f};
            zz = __builtin_amdgcn_mfma_f32_16x16x32_bf16(gfrag[0], wfrag[njl][2], zz, 0, 0, 0);
            dacc[njl] = __builtin_amdgcn_mfma_f32_16x16x32_bf16(gfrag[1], wfrag[njl][3], zz, 0, 0, 0);
        }

        float vm[2] = {0.f, 0.f};
#pragma unroll
        for (int njl = 0; njl < 2; njl++) {
#pragma unroll
            for (int mi = 0; mi < 4; mi++) {
                f32x4 acc = dacc[njl];
                acc = __builtin_amdgcn_mfma_f32_16x16x32_bf16(bz[mi][0], wfrag[njl][0], acc, 0, 0, 0);
                acc = __builtin_amdgcn_mfma_f32_16x16x32_bf16(bz[mi][1], wfrag[njl][1], acc, 0, 0, 0);
                if (STATS) {
#pragma unroll
                    for (int r = 0; r < 4; r++) { as_[njl] += acc[r]; aq[njl] += acc[r] * acc[r]; }
                } else {
#pragma unroll
                    for (int r = 0; r < 4; r++)
                        vm[njl] = fmaxf(vm[njl], fmaxf(fmaf(acc[r], sc1[njl], sh1[njl]), 0.f));
                }
            }
        }

        if (!STATS) {
#pragma unroll
            for (int njl = 0; njl < 2; njl++) {
                float v = vm[njl];
                v = fmaxf(v, __shfl_xor(v, 16));
                v = fmaxf(v, __shfl_xor(v, 32));
                if (l < 16) pout[(size_t)n * 128 + 32 * w + 16 * njl + l] = v;
            }
        }
    }

    if (STATS) {
#pragma unroll
        for (int njl = 0; njl < 2; njl++) {
            float s = as_[njl];
            s += __shfl_xor(s, 16); s += __shfl_xor(s, 32);
            float qq = aq[njl];
            qq += __shfl_xor(qq, 16); qq += __shfl_xor(qq, 32);
            if (l < 16) {
                int col = 32 * w + 16 * njl + l;
                pbuf[col] = s;
                pbuf[128 + col] = qq;
            }
        }
        __syncthreads();
        pout[(size_t)blockIdx.x * 256 + t] = pbuf[t];
    }
}

extern "C" void kernel_launch(void* const* d_in, const int* in_sizes, int n_in,
                              void* d_out, int out_size, void* d_ws, size_t ws_size,
                              hipStream_t stream) {
    (void)in_sizes; (void)n_in; (void)out_size; (void)ws_size;
    const float* x      = (const float*)d_in[0];
    const float* W0     = (const float*)d_in[1];
    const float* gamma0 = (const float*)d_in[2];
    const float* beta0  = (const float*)d_in[3];
    const float* W1     = (const float*)d_in[4];
    const float* gamma1 = (const float*)d_in[5];
    const float* beta1  = (const float*)d_in[6];
    float* out = (float*)d_out;
    float* ws  = (float*)d_ws;

    k_stats0<<<NB0, 256, 0, stream>>>(x, out);                       // partials -> out
    k_finalize0<<<1, 256, 0, stream>>>(out, ws, W0, gamma0, beta0);
    k_pass<true><<<NB1, 256, 0, stream>>>(x, W0, W1, ws, out);       // partials -> out
    k_finalize1<<<128, 256, 0, stream>>>(out, ws, gamma1, beta1);
    k_pass<false><<<NBF, 256, 0, stream>>>(x, W0, W1, ws, out);      // final output
}